// Round 1
// baseline (3924.711 us; speedup 1.0000x reference)
//
#include <hip/hip_runtime.h>
#include <hip/hip_bf16.h>

// ---------------------------------------------------------------------------
// GraphSAGE forward, fp32.
// Pipeline:
//   Wc = W_pre2 @ W_pre, bc = W_pre2 @ b_pre + b_pre2      (tiny)
//   H2 = x @ Wc.T + bc                                     [50000,256]
//   cnt[d] = #edges into d ; agg1[d] += H2[src]            (atomics)
//   H3 = relu( (agg1/cnt) @ Wl1.T + bl1 + H2 @ Wr1.T )     [50000,256]
//   TR = H3 @ [Wl2 ; Wr2].T    (T = cols 0..127, R = cols 128..255)
//   agg2[d] += T[src]                                      (atomics)
//   out = l2norm( agg2/cnt + bl2 + R )                     [50000,128]
// ---------------------------------------------------------------------------

__device__ __forceinline__ void atomic_fadd(float* p, float v) {
  unsafeAtomicAdd(p, v);  // native global_atomic_add_f32 on gfx950
}

__global__ __launch_bounds__(256) void zero_kernel(float4* __restrict__ p, int n4) {
  int i = blockIdx.x * blockDim.x + threadIdx.x;
  const int stride = gridDim.x * blockDim.x;
  for (; i < n4; i += stride) p[i] = make_float4(0.f, 0.f, 0.f, 0.f);
}

__global__ __launch_bounds__(256) void count_kernel(const int* __restrict__ dst,
                                                    float* __restrict__ cntf, int E) {
  const int e = blockIdx.x * blockDim.x + threadIdx.x;
  if (e < E) atomic_fadd(&cntf[dst[e]], 1.0f);
}

// Wc[o][k] = sum_m W_pre2[o][m] * W_pre[m][k]   (o = blockIdx.x, 256 blocks)
__global__ __launch_bounds__(256) void combine_w_kernel(const float* __restrict__ Wp,
                                                        const float* __restrict__ Wp2,
                                                        float* __restrict__ Wc) {
  __shared__ float wrow[256];
  const int o = blockIdx.x, t = threadIdx.x;
  wrow[t] = Wp2[o * 256 + t];
  __syncthreads();
  float a0 = 0.f, a1 = 0.f;
  for (int m = 0; m < 256; ++m) {
    const float w = wrow[m];
    a0 = fmaf(w, Wp[m * 512 + t], a0);
    a1 = fmaf(w, Wp[m * 512 + 256 + t], a1);
  }
  Wc[o * 512 + t] = a0;
  Wc[o * 512 + 256 + t] = a1;
}

__global__ __launch_bounds__(256) void combine_b_kernel(const float* __restrict__ Wp2,
                                                        const float* __restrict__ bp,
                                                        const float* __restrict__ bp2,
                                                        float* __restrict__ bc) {
  const int o = threadIdx.x;
  float s = 0.f;
  for (int m = 0; m < 256; ++m) s = fmaf(Wp2[o * 256 + m], bp[m], s);
  bc[o] = s + bp2[o];
}

// ---------------------------------------------------------------------------
// Tiled fp32 GEMM, C[M,256] = act( A @ B.T + bias ).
// BM=BN=128, BK=8, 256 threads, 8x8 per thread.
// MODE 0: A1[M,512] @ B1[256,512].T + bias            (H2 = x @ Wc.T + bc)
// MODE 1: (A1*inv)[M,256]@B1[256,256].T + A2@B2.T + bias, relu  (conv1)
// MODE 2: A1[M,256] @ [B1[128,256];B2[128,256]].T     (TR = H3 @ [Wl2;Wr2].T)
// ---------------------------------------------------------------------------
template <int MODE>
__global__ __launch_bounds__(256) void gemm_kernel(
    const float* __restrict__ A1, const float* __restrict__ A2,
    const float* __restrict__ B1, const float* __restrict__ B2,
    const float* __restrict__ bias, const float* __restrict__ cntf,
    float* __restrict__ C, int M) {
  constexpr int K = (MODE == 2) ? 256 : 512;
  __shared__ __align__(16) float As[8][132];
  __shared__ __align__(16) float Bs[8][132];
  const int t = threadIdx.x;
  const int bm = blockIdx.x * 128;
  const int bn = blockIdx.y * 128;
  const int lm = t >> 1;          // 0..127 : tile row this thread stages
  const int lk = (t & 1) * 4;     // 0 or 4 : k-offset this thread stages
  const int ty = t >> 4;          // 0..15
  const int tx = t & 15;          // 0..15

  const int arow = bm + lm;
  const bool aok = (arow < M);
  float inv = 0.0f;
  if (MODE == 1) inv = aok ? (1.0f / fmaxf(cntf[arow], 1.0f)) : 0.0f;
  const int brow = bn + lm;       // 0..255, always valid (N=256)
  const float* Brow = nullptr;
  if (MODE == 2)
    Brow = (brow < 128) ? (B1 + (size_t)brow * 256) : (B2 + (size_t)(brow - 128) * 256);

  float acc[8][8];
#pragma unroll
  for (int i = 0; i < 8; ++i)
#pragma unroll
    for (int j = 0; j < 8; ++j) acc[i][j] = 0.f;

  for (int k0 = 0; k0 < K; k0 += 8) {
    float4 av = make_float4(0.f, 0.f, 0.f, 0.f);
    float4 bv;
    if (MODE == 0) {
      if (aok) av = *(const float4*)&A1[(size_t)arow * 512 + k0 + lk];
      bv = *(const float4*)&B1[(size_t)brow * 512 + k0 + lk];
    } else if (MODE == 1) {
      if (k0 < 256) {
        if (aok) {
          av = *(const float4*)&A1[(size_t)arow * 256 + k0 + lk];
          av.x *= inv; av.y *= inv; av.z *= inv; av.w *= inv;
        }
        bv = *(const float4*)&B1[(size_t)brow * 256 + k0 + lk];
      } else {
        if (aok) av = *(const float4*)&A2[(size_t)arow * 256 + (k0 - 256) + lk];
        bv = *(const float4*)&B2[(size_t)brow * 256 + (k0 - 256) + lk];
      }
    } else {
      if (aok) av = *(const float4*)&A1[(size_t)arow * 256 + k0 + lk];
      bv = *(const float4*)&Brow[k0 + lk];
    }
    __syncthreads();
    As[lk + 0][lm] = av.x; As[lk + 1][lm] = av.y;
    As[lk + 2][lm] = av.z; As[lk + 3][lm] = av.w;
    Bs[lk + 0][lm] = bv.x; Bs[lk + 1][lm] = bv.y;
    Bs[lk + 2][lm] = bv.z; Bs[lk + 3][lm] = bv.w;
    __syncthreads();
#pragma unroll
    for (int kk = 0; kk < 8; ++kk) {
      const float4 a0 = *(const float4*)&As[kk][ty * 8];
      const float4 a1 = *(const float4*)&As[kk][ty * 8 + 4];
      const float4 b0 = *(const float4*)&Bs[kk][tx * 8];
      const float4 b1 = *(const float4*)&Bs[kk][tx * 8 + 4];
      const float am[8] = {a0.x, a0.y, a0.z, a0.w, a1.x, a1.y, a1.z, a1.w};
      const float bn8[8] = {b0.x, b0.y, b0.z, b0.w, b1.x, b1.y, b1.z, b1.w};
#pragma unroll
      for (int i = 0; i < 8; ++i)
#pragma unroll
        for (int j = 0; j < 8; ++j) acc[i][j] = fmaf(am[i], bn8[j], acc[i][j]);
    }
  }

#pragma unroll
  for (int i = 0; i < 8; ++i) {
    const int row = bm + ty * 8 + i;
    if (row < M) {
#pragma unroll
      for (int j4 = 0; j4 < 8; j4 += 4) {
        const int col = bn + tx * 8 + j4;
        float4 v = make_float4(acc[i][j4], acc[i][j4 + 1], acc[i][j4 + 2], acc[i][j4 + 3]);
        if (MODE == 0) {
          v.x += bias[col]; v.y += bias[col + 1]; v.z += bias[col + 2]; v.w += bias[col + 3];
        } else if (MODE == 1) {
          v.x = fmaxf(v.x + bias[col], 0.f);
          v.y = fmaxf(v.y + bias[col + 1], 0.f);
          v.z = fmaxf(v.z + bias[col + 2], 0.f);
          v.w = fmaxf(v.w + bias[col + 3], 0.f);
        }
        *(float4*)&C[(size_t)row * 256 + col] = v;
      }
    }
  }
}

// one wave per edge, 4 floats/lane (256-dim rows)
__global__ __launch_bounds__(256) void scatter256_kernel(const float* __restrict__ H,
    const int* __restrict__ src, const int* __restrict__ dst,
    float* __restrict__ agg, int E) {
  const int e = blockIdx.x * 4 + (threadIdx.x >> 6);
  if (e >= E) return;
  const int lane = threadIdx.x & 63;
  const int s = src[e], d = dst[e];
  const float4 v = *(const float4*)&H[(size_t)s * 256 + lane * 4];
  float* p = &agg[(size_t)d * 256 + lane * 4];
  atomic_fadd(p + 0, v.x);
  atomic_fadd(p + 1, v.y);
  atomic_fadd(p + 2, v.z);
  atomic_fadd(p + 3, v.w);
}

// one wave per edge, 2 floats/lane (128-dim rows; T = first 128 cols of TR)
__global__ __launch_bounds__(256) void scatter128_kernel(const float* __restrict__ TR,
    const int* __restrict__ src, const int* __restrict__ dst,
    float* __restrict__ agg, int E) {
  const int e = blockIdx.x * 4 + (threadIdx.x >> 6);
  if (e >= E) return;
  const int lane = threadIdx.x & 63;
  const int s = src[e], d = dst[e];
  const float2 v = *(const float2*)&TR[(size_t)s * 256 + lane * 2];
  float* p = &agg[(size_t)d * 128 + lane * 2];
  atomic_fadd(p + 0, v.x);
  atomic_fadd(p + 1, v.y);
}

// one wave per node: v = agg2/cnt + bl2 + R ; out = v / max(||v||, 1e-12)
__global__ __launch_bounds__(256) void finalize_kernel(const float* __restrict__ agg2,
    const float* __restrict__ TR, const float* __restrict__ cntf,
    const float* __restrict__ bl2, float* __restrict__ out, int M) {
  const int node = blockIdx.x * 4 + (threadIdx.x >> 6);
  if (node >= M) return;
  const int lane = threadIdx.x & 63;
  const float inv = 1.0f / fmaxf(cntf[node], 1.0f);
  const float2 a = *(const float2*)&agg2[(size_t)node * 128 + lane * 2];
  const float2 r = *(const float2*)&TR[(size_t)node * 256 + 128 + lane * 2];
  const float2 b = *(const float2*)&bl2[lane * 2];
  const float vx = fmaf(a.x, inv, b.x) + r.x;
  const float vy = fmaf(a.y, inv, b.y) + r.y;
  float ss = vx * vx + vy * vy;
#pragma unroll
  for (int off = 32; off > 0; off >>= 1) ss += __shfl_xor(ss, off);
  const float rn = 1.0f / fmaxf(sqrtf(ss), 1e-12f);
  *(float2*)&out[(size_t)node * 128 + lane * 2] = make_float2(vx * rn, vy * rn);
}

extern "C" void kernel_launch(void* const* d_in, const int* in_sizes, int n_in,
                              void* d_out, int out_size, void* d_ws, size_t ws_size,
                              hipStream_t stream) {
  const float* x      = (const float*)d_in[0];
  const int*   ei     = (const int*)d_in[1];
  const float* W_pre  = (const float*)d_in[2];
  const float* b_pre  = (const float*)d_in[3];
  const float* W_pre2 = (const float*)d_in[4];
  const float* b_pre2 = (const float*)d_in[5];
  const float* Wl1    = (const float*)d_in[6];
  const float* bl1    = (const float*)d_in[7];
  const float* Wr1    = (const float*)d_in[8];
  const float* Wl2    = (const float*)d_in[9];
  const float* bl2    = (const float*)d_in[10];
  const float* Wr2    = (const float*)d_in[11];
  float* out = (float*)d_out;

  const int M = in_sizes[0] / 512;  // 50000 nodes
  const int E = in_sizes[1] / 2;    // 800000 edges
  const int* src = ei;
  const int* dst = ei + E;

  // workspace layout (floats); TR reuses agg1, agg2 reuses H2 (dead by then)
  float* ws   = (float*)d_ws;
  float* cntf = ws;                            // M (padded region 50000)
  float* agg1 = ws + 50000;                    // M*256
  float* H2   = agg1 + (size_t)M * 256;        // M*256
  float* H3   = H2 + (size_t)M * 256;          // M*256
  float* Wc   = H3 + (size_t)M * 256;          // 256*512
  float* bc   = Wc + 256 * 512;                // 256
  float* TR   = agg1;                          // reuse (agg1 dead after conv1 GEMM)
  float* agg2 = H2;                            // reuse (H2 dead after conv1 GEMM)

  const int eblk = (E + 3) / 4;
  const int mblk = (M + 3) / 4;
  const dim3 gemm_grid((M + 127) / 128, 2);

  // zero cntf + agg1 (contiguous)
  zero_kernel<<<2048, 256, 0, stream>>>((float4*)ws, (50000 + M * 256) / 4);
  count_kernel<<<(E + 255) / 256, 256, 0, stream>>>(dst, cntf, E);
  combine_w_kernel<<<256, 256, 0, stream>>>(W_pre, W_pre2, Wc);
  combine_b_kernel<<<1, 256, 0, stream>>>(W_pre2, b_pre, b_pre2, bc);

  gemm_kernel<0><<<gemm_grid, 256, 0, stream>>>(x, nullptr, Wc, nullptr, bc, nullptr, H2, M);
  scatter256_kernel<<<eblk, 256, 0, stream>>>(H2, src, dst, agg1, E);
  gemm_kernel<1><<<gemm_grid, 256, 0, stream>>>(agg1, H2, Wl1, Wr1, bl1, cntf, H3, M);
  gemm_kernel<2><<<gemm_grid, 256, 0, stream>>>(H3, nullptr, Wl2, Wr2, nullptr, nullptr, TR, M);

  // zero agg2 (the reused H2 region), then scatter T and finalize
  zero_kernel<<<2048, 256, 0, stream>>>((float4*)agg2, (M * 128) / 4);
  scatter128_kernel<<<eblk, 256, 0, stream>>>(TR, src, dst, agg2, E);
  finalize_kernel<<<mblk, 256, 0, stream>>>(agg2, TR, cntf, bl2, out, M);
}

// Round 2
// 987.416 us; speedup vs baseline: 3.9747x; 3.9747x over previous
//
#include <hip/hip_runtime.h>
#include <hip/hip_bf16.h>

// ---------------------------------------------------------------------------
// GraphSAGE forward, fp32, CSR-gather aggregation (no feature atomics).
//   Wc = W_pre2 @ W_pre, bc = W_pre2 @ b_pre + b_pre2
//   H2 = x @ Wc.T + bc                                   [M,256]  (bufA)
//   CSR: cnt -> rowptr -> eidx (ushort)
//   mean1[n] = mean_{src in N(n)} H2[src]                [M,256]  (bufB)
//   H3 = relu(mean1 @ Wl1.T + bl1 + H2 @ Wr1.T)          [M,256]  (bufB, aliased)
//   TR = H3 @ [Wl2 ; Wr2].T                              [M,256]  (bufA)
//   out = l2norm(mean_{src}(T[src]) + bl2 + R)           [M,128]
// ---------------------------------------------------------------------------

__global__ __launch_bounds__(256) void zero_int_kernel(int* __restrict__ p, int n) {
  int i = blockIdx.x * blockDim.x + threadIdx.x;
  const int stride = gridDim.x * blockDim.x;
  for (; i < n; i += stride) p[i] = 0;
}

__global__ __launch_bounds__(256) void count_kernel(const int* __restrict__ dst,
                                                    int* __restrict__ cnt, int E) {
  const int e = blockIdx.x * blockDim.x + threadIdx.x;
  if (e < E) atomicAdd(&cnt[dst[e]], 1);
}

// single-block exclusive scan over cnt -> rowptr; zeroes cnt for cursor reuse
__global__ __launch_bounds__(256) void scan_kernel(int* __restrict__ cnt,
                                                   int* __restrict__ rowptr, int M) {
  __shared__ int buf[256];
  __shared__ int carry;
  const int t = threadIdx.x;
  if (t == 0) carry = 0;
  __syncthreads();
  for (int base = 0; base < M; base += 256) {
    const int i = base + t;
    int v = 0;
    if (i < M) { v = cnt[i]; cnt[i] = 0; }
    buf[t] = v;
    __syncthreads();
    for (int off = 1; off < 256; off <<= 1) {
      const int add = (t >= off) ? buf[t - off] : 0;
      __syncthreads();
      buf[t] += add;
      __syncthreads();
    }
    const int incl = buf[t];
    const int rc = carry;
    if (i < M) rowptr[i] = rc + incl - v;
    __syncthreads();
    if (t == 255) carry = rc + incl;
    __syncthreads();
  }
  if (t == 0) rowptr[M] = carry;
}

__global__ __launch_bounds__(256) void fill_kernel(const int* __restrict__ src,
    const int* __restrict__ dst, const int* __restrict__ rowptr,
    int* __restrict__ cursor, unsigned short* __restrict__ eidx, int E) {
  const int e = blockIdx.x * blockDim.x + threadIdx.x;
  if (e >= E) return;
  const int d = dst[e];
  const int pos = rowptr[d] + atomicAdd(&cursor[d], 1);
  eidx[pos] = (unsigned short)src[e];
}

// Wc[o][k] = sum_m W_pre2[o][m] * W_pre[m][k]
__global__ __launch_bounds__(256) void combine_w_kernel(const float* __restrict__ Wp,
                                                        const float* __restrict__ Wp2,
                                                        float* __restrict__ Wc) {
  __shared__ float wrow[256];
  const int o = blockIdx.x, t = threadIdx.x;
  wrow[t] = Wp2[o * 256 + t];
  __syncthreads();
  float a0 = 0.f, a1 = 0.f;
  for (int m = 0; m < 256; ++m) {
    const float w = wrow[m];
    a0 = fmaf(w, Wp[m * 512 + t], a0);
    a1 = fmaf(w, Wp[m * 512 + 256 + t], a1);
  }
  Wc[o * 512 + t] = a0;
  Wc[o * 512 + 256 + t] = a1;
}

__global__ __launch_bounds__(256) void combine_b_kernel(const float* __restrict__ Wp2,
                                                        const float* __restrict__ bp,
                                                        const float* __restrict__ bp2,
                                                        float* __restrict__ bc) {
  const int o = threadIdx.x;
  float s = 0.f;
  for (int m = 0; m < 256; ++m) s = fmaf(Wp2[o * 256 + m], bp[m], s);
  bc[o] = s + bp2[o];
}

// ---------------------------------------------------------------------------
// Tiled fp32 GEMM, C[M,256] = act(A @ B.T + bias). BM=64, BN=256 (full width:
// each block owns its rows -> C may alias A1). 256 threads, 8x8 per thread.
// MODE 0: A1[M,512] @ B1[256,512].T + bias
// MODE 1: A1[M,256] @ B1.T + A2[M,256] @ B2.T + bias, relu   (C may alias A1)
// MODE 2: A1[M,256] @ [B1[128,256];B2[128,256]].T
// ---------------------------------------------------------------------------
template <int MODE>
__global__ __launch_bounds__(256) void gemm_kernel(
    const float* __restrict__ A1, const float* __restrict__ A2,
    const float* __restrict__ B1, const float* __restrict__ B2,
    const float* __restrict__ bias, float* __restrict__ C, int M) {
  constexpr int K = (MODE == 2) ? 256 : 512;
  __shared__ __align__(16) float As[8][72];
  __shared__ __align__(16) float Bs[8][264];
  const int t = threadIdx.x;
  const int bm = blockIdx.x * 64;
  const int lmA = t >> 2;          // 0..63: A row staged
  const int lkA = (t & 3) * 2;     // 0,2,4,6: k offset (float2)
  const int ty = t >> 5;           // 0..7 -> rows ty*8..+7
  const int tx = t & 31;           // 0..31 -> cols tx*8..+7

  const int arow = bm + lmA;
  const bool aok = (arow < M);
  const float* Brow2 = nullptr;
  if (MODE == 2) Brow2 = (t < 128) ? (B1 + (size_t)t * 256) : (B2 + (size_t)(t - 128) * 256);

  float acc[8][8];
#pragma unroll
  for (int i = 0; i < 8; ++i)
#pragma unroll
    for (int j = 0; j < 8; ++j) acc[i][j] = 0.f;

  for (int k0 = 0; k0 < K; k0 += 8) {
    float2 av = make_float2(0.f, 0.f);
    float4 b0, b1;
    if (MODE == 0) {
      if (aok) av = *(const float2*)&A1[(size_t)arow * 512 + k0 + lkA];
      b0 = *(const float4*)&B1[(size_t)t * 512 + k0];
      b1 = *(const float4*)&B1[(size_t)t * 512 + k0 + 4];
    } else if (MODE == 1) {
      if (k0 < 256) {
        if (aok) av = *(const float2*)&A1[(size_t)arow * 256 + k0 + lkA];
        b0 = *(const float4*)&B1[(size_t)t * 256 + k0];
        b1 = *(const float4*)&B1[(size_t)t * 256 + k0 + 4];
      } else {
        if (aok) av = *(const float2*)&A2[(size_t)arow * 256 + (k0 - 256) + lkA];
        b0 = *(const float4*)&B2[(size_t)t * 256 + (k0 - 256)];
        b1 = *(const float4*)&B2[(size_t)t * 256 + (k0 - 256) + 4];
      }
    } else {
      if (aok) av = *(const float2*)&A1[(size_t)arow * 256 + k0 + lkA];
      b0 = *(const float4*)&Brow2[k0];
      b1 = *(const float4*)&Brow2[k0 + 4];
    }
    __syncthreads();
    As[lkA + 0][lmA] = av.x;
    As[lkA + 1][lmA] = av.y;
    Bs[0][t] = b0.x; Bs[1][t] = b0.y; Bs[2][t] = b0.z; Bs[3][t] = b0.w;
    Bs[4][t] = b1.x; Bs[5][t] = b1.y; Bs[6][t] = b1.z; Bs[7][t] = b1.w;
    __syncthreads();
#pragma unroll
    for (int kk = 0; kk < 8; ++kk) {
      const float4 a0 = *(const float4*)&As[kk][ty * 8];
      const float4 a1 = *(const float4*)&As[kk][ty * 8 + 4];
      const float4 c0 = *(const float4*)&Bs[kk][tx * 8];
      const float4 c1 = *(const float4*)&Bs[kk][tx * 8 + 4];
      const float am[8] = {a0.x, a0.y, a0.z, a0.w, a1.x, a1.y, a1.z, a1.w};
      const float bm8[8] = {c0.x, c0.y, c0.z, c0.w, c1.x, c1.y, c1.z, c1.w};
#pragma unroll
      for (int i = 0; i < 8; ++i)
#pragma unroll
        for (int j = 0; j < 8; ++j) acc[i][j] = fmaf(am[i], bm8[j], acc[i][j]);
    }
  }

#pragma unroll
  for (int i = 0; i < 8; ++i) {
    const int row = bm + ty * 8 + i;
    if (row < M) {
#pragma unroll
      for (int j4 = 0; j4 < 8; j4 += 4) {
        const int col = tx * 8 + j4;
        float4 v = make_float4(acc[i][j4], acc[i][j4 + 1], acc[i][j4 + 2], acc[i][j4 + 3]);
        if (MODE == 0) {
          v.x += bias[col]; v.y += bias[col + 1]; v.z += bias[col + 2]; v.w += bias[col + 3];
        } else if (MODE == 1) {
          v.x = fmaxf(v.x + bias[col], 0.f);
          v.y = fmaxf(v.y + bias[col + 1], 0.f);
          v.z = fmaxf(v.z + bias[col + 2], 0.f);
          v.w = fmaxf(v.w + bias[col + 3], 0.f);
        }
        *(float4*)&C[(size_t)row * 256 + col] = v;
      }
    }
  }
}

// one wave per node: mean of in-neighbor H rows (256-dim, 4 floats/lane)
__global__ __launch_bounds__(256) void gather_mean256_kernel(
    const float* __restrict__ H, const int* __restrict__ rowptr,
    const unsigned short* __restrict__ eidx, float* __restrict__ mean, int M) {
  const int node = blockIdx.x * 4 + (threadIdx.x >> 6);
  if (node >= M) return;
  const int lane = threadIdx.x & 63;
  const int beg = rowptr[node], end = rowptr[node + 1];
  float4 acc = make_float4(0.f, 0.f, 0.f, 0.f);
  int j = beg;
  for (; j + 1 < end; j += 2) {
    const size_t s0 = eidx[j], s1 = eidx[j + 1];
    const float4 v0 = *(const float4*)&H[s0 * 256 + lane * 4];
    const float4 v1 = *(const float4*)&H[s1 * 256 + lane * 4];
    acc.x += v0.x + v1.x; acc.y += v0.y + v1.y;
    acc.z += v0.z + v1.z; acc.w += v0.w + v1.w;
  }
  if (j < end) {
    const size_t s0 = eidx[j];
    const float4 v0 = *(const float4*)&H[s0 * 256 + lane * 4];
    acc.x += v0.x; acc.y += v0.y; acc.z += v0.z; acc.w += v0.w;
  }
  const float inv = 1.0f / fmaxf((float)(end - beg), 1.0f);
  *(float4*)&mean[(size_t)node * 256 + lane * 4] =
      make_float4(acc.x * inv, acc.y * inv, acc.z * inv, acc.w * inv);
}

// one wave per node: v = mean(T[src]) + bl2 + R ; out = v / max(||v||,1e-12)
// T = TR cols 0..127, R = TR cols 128..255
__global__ __launch_bounds__(256) void gather_finalize_kernel(
    const float* __restrict__ TR, const int* __restrict__ rowptr,
    const unsigned short* __restrict__ eidx, const float* __restrict__ bl2,
    float* __restrict__ out, int M) {
  const int node = blockIdx.x * 4 + (threadIdx.x >> 6);
  if (node >= M) return;
  const int lane = threadIdx.x & 63;
  const int beg = rowptr[node], end = rowptr[node + 1];
  float ax = 0.f, ay = 0.f;
  int j = beg;
  for (; j + 1 < end; j += 2) {
    const size_t s0 = eidx[j], s1 = eidx[j + 1];
    const float2 v0 = *(const float2*)&TR[s0 * 256 + lane * 2];
    const float2 v1 = *(const float2*)&TR[s1 * 256 + lane * 2];
    ax += v0.x + v1.x; ay += v0.y + v1.y;
  }
  if (j < end) {
    const size_t s0 = eidx[j];
    const float2 v0 = *(const float2*)&TR[s0 * 256 + lane * 2];
    ax += v0.x; ay += v0.y;
  }
  const float inv = 1.0f / fmaxf((float)(end - beg), 1.0f);
  const float2 r = *(const float2*)&TR[(size_t)node * 256 + 128 + lane * 2];
  const float2 b = *(const float2*)&bl2[lane * 2];
  const float vx = fmaf(ax, inv, b.x) + r.x;
  const float vy = fmaf(ay, inv, b.y) + r.y;
  float ss = vx * vx + vy * vy;
#pragma unroll
  for (int off = 32; off > 0; off >>= 1) ss += __shfl_xor(ss, off);
  const float rn = 1.0f / fmaxf(sqrtf(ss), 1e-12f);
  *(float2*)&out[(size_t)node * 128 + lane * 2] = make_float2(vx * rn, vy * rn);
}

extern "C" void kernel_launch(void* const* d_in, const int* in_sizes, int n_in,
                              void* d_out, int out_size, void* d_ws, size_t ws_size,
                              hipStream_t stream) {
  const float* x      = (const float*)d_in[0];
  const int*   ei     = (const int*)d_in[1];
  const float* W_pre  = (const float*)d_in[2];
  const float* b_pre  = (const float*)d_in[3];
  const float* W_pre2 = (const float*)d_in[4];
  const float* b_pre2 = (const float*)d_in[5];
  const float* Wl1    = (const float*)d_in[6];
  const float* bl1    = (const float*)d_in[7];
  const float* Wr1    = (const float*)d_in[8];
  const float* Wl2    = (const float*)d_in[9];
  const float* bl2    = (const float*)d_in[10];
  const float* Wr2    = (const float*)d_in[11];
  float* out = (float*)d_out;

  const int M = in_sizes[0] / 512;  // 50000
  const int E = in_sizes[1] / 2;    // 800000
  const int* src = ei;
  const int* dst = ei + E;

  // workspace: bufA[M*256] | bufB[M*256] | Wc[256*512] | bc[256]
  //            | rowptr[M+1] | cnt[M] | eidx[E] (ushort)   (~105 MB)
  float* bufA = (float*)d_ws;                  // H2, later TR
  float* bufB = bufA + (size_t)M * 256;        // mean1, later H3 (aliased)
  float* Wc   = bufB + (size_t)M * 256;
  float* bc   = Wc + 256 * 512;
  int* rowptr = (int*)(bc + 256);
  int* cnt    = rowptr + (M + 1);              // doubles as fill cursor
  unsigned short* eidx = (unsigned short*)(cnt + M);

  const int eblk = (E + 255) / 256;
  const int gx   = (M + 63) / 64;
  const int nblk = (M + 3) / 4;

  // CSR build
  zero_int_kernel<<<256, 256, 0, stream>>>(cnt, M);
  count_kernel<<<eblk, 256, 0, stream>>>(dst, cnt, E);
  scan_kernel<<<1, 256, 0, stream>>>(cnt, rowptr, M);
  fill_kernel<<<eblk, 256, 0, stream>>>(src, dst, rowptr, cnt, eidx, E);

  // folded pre-MLP
  combine_w_kernel<<<256, 256, 0, stream>>>(W_pre, W_pre2, Wc);
  combine_b_kernel<<<1, 256, 0, stream>>>(W_pre2, b_pre, b_pre2, bc);

  gemm_kernel<0><<<gx, 256, 0, stream>>>(x, nullptr, Wc, nullptr, bc, bufA, M);
  gather_mean256_kernel<<<nblk, 256, 0, stream>>>(bufA, rowptr, eidx, bufB, M);
  gemm_kernel<1><<<gx, 256, 0, stream>>>(bufB, bufA, Wl1, Wr1, bl1, bufB, M);
  gemm_kernel<2><<<gx, 256, 0, stream>>>(bufB, nullptr, Wl2, Wr2, nullptr, bufA, M);
  gather_finalize_kernel<<<nblk, 256, 0, stream>>>(bufA, rowptr, eidx, bl2, out, M);
}

// Round 3
// 333.307 us; speedup vs baseline: 11.7751x; 2.9625x over previous
//
#include <hip/hip_runtime.h>
#include <hip/hip_bf16.h>

// ---------------------------------------------------------------------------
// GraphSAGE forward, bf16 MFMA GEMMs + CSR gather aggregation.
//   Wc  = bf16(W_pre2 @ W_pre), bc = W_pre2 @ b_pre + b_pre2
//   Acat[M,512] bf16: cols 0..255 = mean1, cols 256..511 = H2 (later TR)
//   H2  = x @ Wc.T + bc            (MFMA, fp32 x reg-staged to bf16)
//   mean1[n] = mean_{s in N(n)} H2[s]
//   H3  = relu(Acat @ [Wl1|Wr1].T + bl1)        (single K=512 MFMA GEMM)
//   TR  = H3 @ [Wl2;Wr2].T  -> overwrites Acat cols 256..511
//   out = l2norm(mean_s(T[s]) + bl2 + R)
// ---------------------------------------------------------------------------

typedef __attribute__((ext_vector_type(4))) float f32x4;
typedef __attribute__((ext_vector_type(8))) short s8v;

__device__ __forceinline__ float bf2f(unsigned short u) {
  union { unsigned int i; float f; } v; v.i = ((unsigned int)u) << 16; return v.f;
}
__device__ __forceinline__ unsigned short f2bf(float f) {
  unsigned int u = __builtin_bit_cast(unsigned int, f);
  u += 0x7fffu + ((u >> 16) & 1u);          // round-to-nearest-even
  return (unsigned short)(u >> 16);
}

// ------------------------------ CSR build ----------------------------------
__global__ __launch_bounds__(256) void zero_int_kernel(int* __restrict__ p, int n) {
  int i = blockIdx.x * blockDim.x + threadIdx.x;
  const int stride = gridDim.x * blockDim.x;
  for (; i < n; i += stride) p[i] = 0;
}

__global__ __launch_bounds__(256) void count_kernel(const int* __restrict__ dst,
                                                    int* __restrict__ cnt, int E) {
  const int e = blockIdx.x * blockDim.x + threadIdx.x;
  if (e < E) atomicAdd(&cnt[dst[e]], 1);
}

__global__ __launch_bounds__(256) void scan_pass1(const int* __restrict__ cnt,
                                                  int* __restrict__ bsum, int M) {
  __shared__ int red[256];
  const int t = threadIdx.x;
  const int i = blockIdx.x * 256 + t;
  red[t] = (i < M) ? cnt[i] : 0;
  __syncthreads();
  for (int off = 128; off > 0; off >>= 1) {
    if (t < off) red[t] += red[t + off];
    __syncthreads();
  }
  if (t == 0) bsum[blockIdx.x] = red[0];
}

__global__ __launch_bounds__(256) void scan_pass2(const int* __restrict__ bsum,
    int* __restrict__ boff, int* __restrict__ rowptr, int nb, int M, int E) {
  __shared__ int buf[256];
  const int t = threadIdx.x;
  const int v = (t < nb) ? bsum[t] : 0;
  buf[t] = v;
  __syncthreads();
  for (int off = 1; off < 256; off <<= 1) {
    const int add = (t >= off) ? buf[t - off] : 0;
    __syncthreads();
    buf[t] += add;
    __syncthreads();
  }
  if (t < nb) boff[t] = buf[t] - v;
  if (t == 0) rowptr[M] = E;
}

__global__ __launch_bounds__(256) void scan_pass3(int* __restrict__ cnt,
    const int* __restrict__ boff, int* __restrict__ rowptr, int M) {
  __shared__ int buf[256];
  const int t = threadIdx.x;
  const int i = blockIdx.x * 256 + t;
  const int v = (i < M) ? cnt[i] : 0;
  buf[t] = v;
  __syncthreads();
  for (int off = 1; off < 256; off <<= 1) {
    const int add = (t >= off) ? buf[t - off] : 0;
    __syncthreads();
    buf[t] += add;
    __syncthreads();
  }
  if (i < M) {
    rowptr[i] = buf[t] - v + boff[blockIdx.x];
    cnt[i] = 0;   // reset for fill cursor
  }
}

__global__ __launch_bounds__(256) void fill_kernel(const int* __restrict__ src,
    const int* __restrict__ dst, const int* __restrict__ rowptr,
    int* __restrict__ cursor, unsigned short* __restrict__ eidx, int E) {
  const int e = blockIdx.x * blockDim.x + threadIdx.x;
  if (e >= E) return;
  const int d = dst[e];
  const int pos = rowptr[d] + atomicAdd(&cursor[d], 1);
  eidx[pos] = (unsigned short)src[e];
}

// --------------------------- weight preparation ----------------------------
__global__ __launch_bounds__(256) void combine_w_kernel(const float* __restrict__ Wp,
    const float* __restrict__ Wp2, unsigned short* __restrict__ Wc) {
  __shared__ float wrow[256];
  const int o = blockIdx.x, t = threadIdx.x;
  wrow[t] = Wp2[o * 256 + t];
  __syncthreads();
  float a0 = 0.f, a1 = 0.f;
  for (int m = 0; m < 256; ++m) {
    const float w = wrow[m];
    a0 = fmaf(w, Wp[m * 512 + t], a0);
    a1 = fmaf(w, Wp[m * 512 + 256 + t], a1);
  }
  Wc[o * 512 + t] = f2bf(a0);
  Wc[o * 512 + 256 + t] = f2bf(a1);
}

__global__ __launch_bounds__(256) void combine_b_kernel(const float* __restrict__ Wp2,
    const float* __restrict__ bp, const float* __restrict__ bp2, float* __restrict__ bc) {
  const int o = threadIdx.x;
  float s = 0.f;
  for (int m = 0; m < 256; ++m) s = fmaf(Wp2[o * 256 + m], bp[m], s);
  bc[o] = s + bp2[o];
}

// Bc1[o][k] = Wl1[o][k] (k<256) | Wr1[o][k-256]
__global__ __launch_bounds__(256) void pack_b1_kernel(const float* __restrict__ Wl1,
    const float* __restrict__ Wr1, unsigned short* __restrict__ Bc1) {
  const int idx = blockIdx.x * 256 + threadIdx.x;   // < 256*512
  const int o = idx >> 9, k = idx & 511;
  const float v = (k < 256) ? Wl1[o * 256 + k] : Wr1[o * 256 + (k - 256)];
  Bc1[idx] = f2bf(v);
}

// Bc2[r][k] = Wl2[r][k] (r<128) | Wr2[r-128][k]
__global__ __launch_bounds__(256) void pack_b2_kernel(const float* __restrict__ Wl2,
    const float* __restrict__ Wr2, unsigned short* __restrict__ Bc2) {
  const int idx = blockIdx.x * 256 + threadIdx.x;   // < 256*256
  const int r = idx >> 8, k = idx & 255;
  const float v = (r < 128) ? Wl2[r * 256 + k] : Wr2[(r - 128) * 256 + k];
  Bc2[idx] = f2bf(v);
}

// ---------------------------------------------------------------------------
// MFMA GEMM: C[M,256] = act(A[M,K] @ B[256,K].T + bias), bf16 in, fp32 acc,
// bf16 out. BM=64, BN=256, BK=32. 256 threads = 4 waves; wave w owns the
// 64x64 quadrant at cols w*64. LDS XOR-swizzle slot^=(row>>1)&3 applied on
// the *source* side (global_load_lds writes linearly); ds_read_b128 frag
// reads are then 2-way (free).
// ---------------------------------------------------------------------------
template <int K, int ASTRIDE, int CSTRIDE, int CBASE, bool BIAS_EN, bool RELU_EN, bool A_FP32>
__global__ __launch_bounds__(256) void mfma_gemm(const void* __restrict__ Ap,
    const unsigned short* __restrict__ Bp, const float* __restrict__ bias,
    unsigned short* __restrict__ Cp, int M) {
  __shared__ __align__(16) char smem[4096 + 16384];
  char* const Asb = smem;          // 64 rows x 64 B
  char* const Bsb = smem + 4096;   // 256 rows x 64 B

  const int t = threadIdx.x, w = t >> 6, l = t & 63;
  const int bm = blockIdx.x * 64;
  const int lr = l >> 2;                    // row within 16-row chunk
  const int ls = l & 3;                     // physical 16B slot
  const int lss = ls ^ ((l >> 3) & 3);      // pre-swizzled logical slot
  const int arow = min(bm + w * 16 + lr, M - 1);
  const int lane15 = l & 15, half = l >> 4;

  float bias_l[4];
  if (BIAS_EN) {
#pragma unroll
    for (int ns = 0; ns < 4; ++ns) bias_l[ns] = bias[w * 64 + ns * 16 + lane15];
  }

  f32x4 acc[4][4];
#pragma unroll
  for (int i = 0; i < 4; ++i)
#pragma unroll
    for (int j = 0; j < 4; ++j) acc[i][j] = f32x4{0.f, 0.f, 0.f, 0.f};

#pragma unroll 1
  for (int k0 = 0; k0 < K; k0 += 32) {
    __syncthreads();   // previous tile fully consumed
    if (A_FP32) {
      const float* ap = (const float*)Ap + (size_t)arow * ASTRIDE + k0 + lss * 8;
      const float4 f0 = *(const float4*)ap;
      const float4 f1 = *(const float4*)(ap + 4);
      s8v pk;
      pk[0] = (short)f2bf(f0.x); pk[1] = (short)f2bf(f0.y);
      pk[2] = (short)f2bf(f0.z); pk[3] = (short)f2bf(f0.w);
      pk[4] = (short)f2bf(f1.x); pk[5] = (short)f2bf(f1.y);
      pk[6] = (short)f2bf(f1.z); pk[7] = (short)f2bf(f1.w);
      *(s8v*)(Asb + w * 1024 + l * 16) = pk;
    } else {
      const unsigned short* ap =
          (const unsigned short*)Ap + (size_t)arow * ASTRIDE + k0 + lss * 8;
      __builtin_amdgcn_global_load_lds(ap, Asb + w * 1024, 16, 0, 0);
    }
#pragma unroll
    for (int i = 0; i < 4; ++i) {
      const int c = w * 4 + i;
      const unsigned short* bp = Bp + (size_t)(c * 16 + lr) * K + k0 + lss * 8;
      __builtin_amdgcn_global_load_lds(bp, Bsb + c * 1024, 16, 0, 0);
    }
    __syncthreads();   // staging complete

    s8v af[4], bf[4];
#pragma unroll
    for (int ms = 0; ms < 4; ++ms) {
      const int r = ms * 16 + lane15;
      af[ms] = *(const s8v*)(Asb + r * 64 + ((half ^ ((r >> 1) & 3)) << 4));
    }
#pragma unroll
    for (int ns = 0; ns < 4; ++ns) {
      const int r = w * 64 + ns * 16 + lane15;
      bf[ns] = *(const s8v*)(Bsb + r * 64 + ((half ^ ((r >> 1) & 3)) << 4));
    }
#pragma unroll
    for (int ms = 0; ms < 4; ++ms)
#pragma unroll
      for (int ns = 0; ns < 4; ++ns)
        acc[ms][ns] =
            __builtin_amdgcn_mfma_f32_16x16x32_bf16(af[ms], bf[ns], acc[ms][ns], 0, 0, 0);
  }

#pragma unroll
  for (int ms = 0; ms < 4; ++ms)
#pragma unroll
    for (int ns = 0; ns < 4; ++ns) {
      const int col = w * 64 + ns * 16 + lane15;
      f32x4 v = acc[ms][ns];
      if (BIAS_EN) {
#pragma unroll
        for (int r = 0; r < 4; ++r) v[r] += bias_l[ns];
      }
      if (RELU_EN) {
#pragma unroll
        for (int r = 0; r < 4; ++r) v[r] = fmaxf(v[r], 0.f);
      }
#pragma unroll
      for (int r = 0; r < 4; ++r) {
        const int row = bm + ms * 16 + half * 4 + r;
        if (row < M) Cp[(size_t)row * CSTRIDE + CBASE + col] = f2bf(v[r]);
      }
    }
}

// ------------------------------- gathers -----------------------------------
// one wave per node: mean of in-neighbor H2 rows (bf16, Acat cols 256..511)
__global__ __launch_bounds__(256) void gather_mean256_kernel(
    unsigned short* __restrict__ Acat, const int* __restrict__ rowptr,
    const unsigned short* __restrict__ eidx, int M) {
  const int node = blockIdx.x * 4 + (threadIdx.x >> 6);
  if (node >= M) return;
  const int lane = threadIdx.x & 63;
  const int c4 = lane * 4;
  const int beg = rowptr[node], end = rowptr[node + 1];
  float a0 = 0.f, a1 = 0.f, a2 = 0.f, a3 = 0.f;
  int j = beg;
  for (; j + 1 < end; j += 2) {
    const size_t s0 = eidx[j], s1 = eidx[j + 1];
    const ushort4 v0 = *(const ushort4*)(Acat + s0 * 512 + 256 + c4);
    const ushort4 v1 = *(const ushort4*)(Acat + s1 * 512 + 256 + c4);
    a0 += bf2f(v0.x) + bf2f(v1.x); a1 += bf2f(v0.y) + bf2f(v1.y);
    a2 += bf2f(v0.z) + bf2f(v1.z); a3 += bf2f(v0.w) + bf2f(v1.w);
  }
  if (j < end) {
    const size_t s0 = eidx[j];
    const ushort4 v0 = *(const ushort4*)(Acat + s0 * 512 + 256 + c4);
    a0 += bf2f(v0.x); a1 += bf2f(v0.y); a2 += bf2f(v0.z); a3 += bf2f(v0.w);
  }
  const float inv = 1.0f / fmaxf((float)(end - beg), 1.0f);
  ushort4 o;
  o.x = f2bf(a0 * inv); o.y = f2bf(a1 * inv);
  o.z = f2bf(a2 * inv); o.w = f2bf(a3 * inv);
  *(ushort4*)(Acat + (size_t)node * 512 + c4) = o;
}

// one wave per node: v = mean(T[src]) + bl2 + R ; out = v / max(||v||,1e-12)
// T = Acat cols 256..383, R = Acat cols 384..511
__global__ __launch_bounds__(256) void gather_finalize_kernel(
    const unsigned short* __restrict__ Acat, const int* __restrict__ rowptr,
    const unsigned short* __restrict__ eidx, const float* __restrict__ bl2,
    float* __restrict__ out, int M) {
  const int node = blockIdx.x * 4 + (threadIdx.x >> 6);
  if (node >= M) return;
  const int lane = threadIdx.x & 63;
  const int c2 = lane * 2;
  const int beg = rowptr[node], end = rowptr[node + 1];
  float ax = 0.f, ay = 0.f;
  int j = beg;
  for (; j + 1 < end; j += 2) {
    const size_t s0 = eidx[j], s1 = eidx[j + 1];
    const ushort2 v0 = *(const ushort2*)(Acat + s0 * 512 + 256 + c2);
    const ushort2 v1 = *(const ushort2*)(Acat + s1 * 512 + 256 + c2);
    ax += bf2f(v0.x) + bf2f(v1.x); ay += bf2f(v0.y) + bf2f(v1.y);
  }
  if (j < end) {
    const size_t s0 = eidx[j];
    const ushort2 v0 = *(const ushort2*)(Acat + s0 * 512 + 256 + c2);
    ax += bf2f(v0.x); ay += bf2f(v0.y);
  }
  const float inv = 1.0f / fmaxf((float)(end - beg), 1.0f);
  const ushort2 rr = *(const ushort2*)(Acat + (size_t)node * 512 + 384 + c2);
  const float2 b = *(const float2*)&bl2[c2];
  const float vx = fmaf(ax, inv, b.x) + bf2f(rr.x);
  const float vy = fmaf(ay, inv, b.y) + bf2f(rr.y);
  float ss = vx * vx + vy * vy;
#pragma unroll
  for (int off = 32; off > 0; off >>= 1) ss += __shfl_xor(ss, off);
  const float rn = 1.0f / fmaxf(sqrtf(ss), 1e-12f);
  *(float2*)&out[(size_t)node * 128 + c2] = make_float2(vx * rn, vy * rn);
}

// ---------------------------------------------------------------------------
extern "C" void kernel_launch(void* const* d_in, const int* in_sizes, int n_in,
                              void* d_out, int out_size, void* d_ws, size_t ws_size,
                              hipStream_t stream) {
  const float* x      = (const float*)d_in[0];
  const int*   ei     = (const int*)d_in[1];
  const float* W_pre  = (const float*)d_in[2];
  const float* b_pre  = (const float*)d_in[3];
  const float* W_pre2 = (const float*)d_in[4];
  const float* b_pre2 = (const float*)d_in[5];
  const float* Wl1    = (const float*)d_in[6];
  const float* bl1    = (const float*)d_in[7];
  const float* Wr1    = (const float*)d_in[8];
  const float* Wl2    = (const float*)d_in[9];
  const float* bl2    = (const float*)d_in[10];
  const float* Wr2    = (const float*)d_in[11];
  float* out = (float*)d_out;

  const int M = in_sizes[0] / 512;  // 50000
  const int E = in_sizes[1] / 2;    // 800000
  const int* src = ei;
  const int* dst = ei + E;

  // workspace (bytes): Acat bf16[M*512] | H3 bf16[M*256] | Wc[256*512] |
  //   Bc1[256*512] | Bc2[256*256] | bc f32[256] | rowptr[M+1] | cnt[M] |
  //   bsum[256] | boff[256] | eidx ushort[E]          (~80 MB)
  char* p = (char*)d_ws;
  unsigned short* Acat = (unsigned short*)p; p += (size_t)M * 512 * 2;
  unsigned short* H3   = (unsigned short*)p; p += (size_t)M * 256 * 2;
  unsigned short* Wc   = (unsigned short*)p; p += 256 * 512 * 2;
  unsigned short* Bc1  = (unsigned short*)p; p += 256 * 512 * 2;
  unsigned short* Bc2  = (unsigned short*)p; p += 256 * 256 * 2;
  float* bc   = (float*)p; p += 256 * 4;
  int* rowptr = (int*)p;   p += (size_t)(M + 1) * 4;
  int* cnt    = (int*)p;   p += (size_t)M * 4;
  int* bsum   = (int*)p;   p += 256 * 4;
  int* boff   = (int*)p;   p += 256 * 4;
  unsigned short* eidx = (unsigned short*)p;

  const int eblk = (E + 255) / 256;
  const int nb   = (M + 255) / 256;   // 196
  const int gx   = (M + 63) / 64;     // 782
  const int nblk = (M + 3) / 4;

  // CSR build
  zero_int_kernel<<<256, 256, 0, stream>>>(cnt, M);
  count_kernel<<<eblk, 256, 0, stream>>>(dst, cnt, E);
  scan_pass1<<<nb, 256, 0, stream>>>(cnt, bsum, M);
  scan_pass2<<<1, 256, 0, stream>>>(bsum, boff, rowptr, nb, M, E);
  scan_pass3<<<nb, 256, 0, stream>>>(cnt, boff, rowptr, M);
  fill_kernel<<<eblk, 256, 0, stream>>>(src, dst, rowptr, cnt, eidx, E);

  // weights
  combine_w_kernel<<<256, 256, 0, stream>>>(W_pre, W_pre2, Wc);
  combine_b_kernel<<<1, 256, 0, stream>>>(W_pre2, b_pre, b_pre2, bc);
  pack_b1_kernel<<<512, 256, 0, stream>>>(Wl1, Wr1, Bc1);
  pack_b2_kernel<<<256, 256, 0, stream>>>(Wl2, Wr2, Bc2);

  // H2 = x @ Wc.T + bc  -> Acat cols 256..511
  mfma_gemm<512, 512, 512, 256, true, false, true>
      <<<gx, 256, 0, stream>>>(x, Wc, bc, Acat, M);
  // mean1 -> Acat cols 0..255
  gather_mean256_kernel<<<nblk, 256, 0, stream>>>(Acat, rowptr, eidx, M);
  // H3 = relu(Acat @ Bc1.T + bl1)
  mfma_gemm<512, 512, 256, 0, true, true, false>
      <<<gx, 256, 0, stream>>>(Acat, Bc1, bl1, H3, M);
  // TR = H3 @ Bc2.T -> Acat cols 256..511 (H2 dead)
  mfma_gemm<256, 256, 512, 256, false, false, false>
      <<<gx, 256, 0, stream>>>(H3, Bc2, nullptr, Acat, M);
  // out = l2norm(mean(T) + bl2 + R)
  gather_finalize_kernel<<<nblk, 256, 0, stream>>>(Acat, rowptr, eidx, bl2, out, M);
}

// Round 5
// 275.511 us; speedup vs baseline: 14.2452x; 1.2098x over previous
//
#include <hip/hip_runtime.h>
#include <hip/hip_bf16.h>

// ---------------------------------------------------------------------------
// GraphSAGE forward, bf16 MFMA GEMMs (2-phase pipelined) + CSR gather.
//   Wc  = bf16(W_pre2 @ W_pre), bc = W_pre2 @ b_pre + b_pre2
//   Acat[M,512] bf16: cols 0..255 = mean1, cols 256..511 = H2 (later TR)
//   H2  = x @ Wc.T + bc            (MFMA, fp32 x reg-staged to bf16)
//   mean1[n] = mean_{s in N(n)} H2[s]
//   H3  = relu(Acat @ [Wl1|Wr1].T + bl1)        (single K=512 MFMA GEMM)
//   TR  = H3 @ [Wl2;Wr2].T  -> overwrites Acat cols 256..511
//   out = l2norm(mean_s(T[s]) + bl2 + R)
// GEMM: BM=64, BN=256, BK=64, 4 waves; double-buffered LDS, stage(t+1)
// issued BEFORE compute(t), one __syncthreads (vmcnt drain) per K-tile.
// NOTE: LDS double-buffer bases computed via smem + cur*OFFSET arithmetic —
// arrays of __shared__-derived pointers fail to compile (addrspacecast in
// static initializer).
// ---------------------------------------------------------------------------

typedef __attribute__((ext_vector_type(4))) float f32x4;
typedef __attribute__((ext_vector_type(8))) short s8v;

#define A_BUF_SZ 8192
#define B_BUF_SZ 32768
#define B_BASE   (2 * A_BUF_SZ)

__device__ __forceinline__ float bf2f(unsigned short u) {
  union { unsigned int i; float f; } v; v.i = ((unsigned int)u) << 16; return v.f;
}
__device__ __forceinline__ unsigned short f2bf(float f) {
  unsigned int u = __builtin_bit_cast(unsigned int, f);
  u += 0x7fffu + ((u >> 16) & 1u);          // round-to-nearest-even
  return (unsigned short)(u >> 16);
}

// ------------------------------ CSR build ----------------------------------
__global__ __launch_bounds__(256) void zero_int_kernel(int* __restrict__ p, int n) {
  int i = blockIdx.x * blockDim.x + threadIdx.x;
  const int stride = gridDim.x * blockDim.x;
  for (; i < n; i += stride) p[i] = 0;
}

__global__ __launch_bounds__(256) void count_kernel(const int* __restrict__ dst,
                                                    int* __restrict__ cnt, int E) {
  const int e = blockIdx.x * blockDim.x + threadIdx.x;
  if (e < E) atomicAdd(&cnt[dst[e]], 1);
}

__global__ __launch_bounds__(256) void scan_pass1(const int* __restrict__ cnt,
                                                  int* __restrict__ bsum, int M) {
  __shared__ int red[256];
  const int t = threadIdx.x;
  const int i = blockIdx.x * 256 + t;
  red[t] = (i < M) ? cnt[i] : 0;
  __syncthreads();
  for (int off = 128; off > 0; off >>= 1) {
    if (t < off) red[t] += red[t + off];
    __syncthreads();
  }
  if (t == 0) bsum[blockIdx.x] = red[0];
}

__global__ __launch_bounds__(256) void scan_pass2(const int* __restrict__ bsum,
    int* __restrict__ boff, int* __restrict__ rowptr, int nb, int M, int E) {
  __shared__ int buf[256];
  const int t = threadIdx.x;
  const int v = (t < nb) ? bsum[t] : 0;
  buf[t] = v;
  __syncthreads();
  for (int off = 1; off < 256; off <<= 1) {
    const int add = (t >= off) ? buf[t - off] : 0;
    __syncthreads();
    buf[t] += add;
    __syncthreads();
  }
  if (t < nb) boff[t] = buf[t] - v;
  if (t == 0) rowptr[M] = E;
}

__global__ __launch_bounds__(256) void scan_pass3(int* __restrict__ cnt,
    const int* __restrict__ boff, int* __restrict__ rowptr, int M) {
  __shared__ int buf[256];
  const int t = threadIdx.x;
  const int i = blockIdx.x * 256 + t;
  const int v = (i < M) ? cnt[i] : 0;
  buf[t] = v;
  __syncthreads();
  for (int off = 1; off < 256; off <<= 1) {
    const int add = (t >= off) ? buf[t - off] : 0;
    __syncthreads();
    buf[t] += add;
    __syncthreads();
  }
  if (i < M) {
    rowptr[i] = buf[t] - v + boff[blockIdx.x];
    cnt[i] = 0;   // reset for fill cursor
  }
}

__global__ __launch_bounds__(256) void fill_kernel(const int* __restrict__ src,
    const int* __restrict__ dst, const int* __restrict__ rowptr,
    int* __restrict__ cursor, unsigned short* __restrict__ eidx, int E) {
  const int e = blockIdx.x * blockDim.x + threadIdx.x;
  if (e >= E) return;
  const int d = dst[e];
  const int pos = rowptr[d] + atomicAdd(&cursor[d], 1);
  eidx[pos] = (unsigned short)src[e];
}

// --------------------- fused weight preparation ----------------------------
// blocks 0..255: Wc row o ; block 256: bc ; 257..768: Bc1 ; 769..1024: Bc2
__global__ __launch_bounds__(256) void prep_kernel(const float* __restrict__ Wp,
    const float* __restrict__ Wp2, const float* __restrict__ bp,
    const float* __restrict__ bp2, const float* __restrict__ Wl1,
    const float* __restrict__ Wr1, const float* __restrict__ Wl2,
    const float* __restrict__ Wr2, unsigned short* __restrict__ Wc,
    float* __restrict__ bc, unsigned short* __restrict__ Bc1,
    unsigned short* __restrict__ Bc2) {
  const int b = blockIdx.x, t = threadIdx.x;
  if (b < 256) {
    __shared__ float wrow[256];
    wrow[t] = Wp2[b * 256 + t];
    __syncthreads();
    float a0 = 0.f, a1 = 0.f;
    for (int m = 0; m < 256; ++m) {
      const float w = wrow[m];
      a0 = fmaf(w, Wp[m * 512 + t], a0);
      a1 = fmaf(w, Wp[m * 512 + 256 + t], a1);
    }
    Wc[b * 512 + t] = f2bf(a0);
    Wc[b * 512 + 256 + t] = f2bf(a1);
  } else if (b == 256) {
    float s = 0.f;
    for (int m = 0; m < 256; ++m) s = fmaf(Wp2[t * 256 + m], bp[m], s);
    bc[t] = s + bp2[t];
  } else if (b < 769) {
    const int idx = (b - 257) * 256 + t;   // < 256*512
    const int o = idx >> 9, k = idx & 511;
    const float v = (k < 256) ? Wl1[o * 256 + k] : Wr1[o * 256 + (k - 256)];
    Bc1[idx] = f2bf(v);
  } else {
    const int idx = (b - 769) * 256 + t;   // < 256*256
    const int r = idx >> 8, k = idx & 255;
    const float v = (r < 128) ? Wl2[r * 256 + k] : Wr2[(r - 128) * 256 + k];
    Bc2[idx] = f2bf(v);
  }
}

// ---------------------------------------------------------------------------
// Pipelined MFMA GEMM: C[M,256] = act(A[M,K] @ B[256,K].T + bias).
// ---------------------------------------------------------------------------
template <int K, int ASTRIDE, int CSTRIDE, int CBASE, bool BIAS_EN, bool RELU_EN, bool A_FP32>
__global__ __launch_bounds__(256) void mfma_gemm(const void* __restrict__ Ap,
    const unsigned short* __restrict__ Bp, const float* __restrict__ bias,
    unsigned short* __restrict__ Cp, int M) {
  constexpr int NT = K / 64;
  __shared__ __align__(16) char smem[2 * A_BUF_SZ + 2 * B_BUF_SZ];  // 80 KB

  const int t = threadIdx.x, w = t >> 6, l = t & 63;
  const int bm = blockIdx.x * 64;
  const int lane15 = l & 15, half = (l >> 4) & 3;

  float bias_l[4];
  if (BIAS_EN) {
#pragma unroll
    for (int ns = 0; ns < 4; ++ns) bias_l[ns] = bias[w * 64 + ns * 16 + lane15];
  }

  f32x4 acc[4][4];
#pragma unroll
  for (int i = 0; i < 4; ++i)
#pragma unroll
    for (int j = 0; j < 4; ++j) acc[i][j] = f32x4{0.f, 0.f, 0.f, 0.f};

  // --- staging helpers (LDS layout: row-major, 8x16B swizzled slots/row) ---
  auto stageB = [&](char* dstB, int k0) {
#pragma unroll
    for (int i = 0; i < 8; ++i) {
      const int c = i * 256 + t;
      const int rB = c >> 3;
      const int sl = (c & 7) ^ (rB & 7);
      __builtin_amdgcn_global_load_lds(
          (const unsigned int*)(Bp + (size_t)rB * K + k0 + sl * 8),
          (unsigned int*)(dstB + i * 4096 + w * 1024), 16, 0, 0);
    }
  };
  auto stageA_bf16 = [&](char* dstA, int k0) {
#pragma unroll
    for (int i = 0; i < 2; ++i) {
      const int c = w * 128 + i * 64 + l;
      const int rA = c >> 3;
      const int sl = (c & 7) ^ (rA & 7);
      const unsigned short* ap = (const unsigned short*)Ap +
          (size_t)min(bm + rA, M - 1) * ASTRIDE + k0 + sl * 8;
      __builtin_amdgcn_global_load_lds((const unsigned int*)ap,
          (unsigned int*)(dstA + w * 2048 + i * 1024), 16, 0, 0);
    }
  };
  const int rAf = t >> 2;                         // fp32-A path: row staged
  const int arowf = min(bm + rAf, M - 1);
  const int phys0 = ((t & 3) * 2) ^ (rAf & 7);
  auto loadA_f32 = [&](int k0, float4* ar) {
    const float* ap = (const float*)Ap + (size_t)arowf * ASTRIDE + k0 + (t & 3) * 16;
    ar[0] = *(const float4*)(ap + 0);
    ar[1] = *(const float4*)(ap + 4);
    ar[2] = *(const float4*)(ap + 8);
    ar[3] = *(const float4*)(ap + 12);
  };
  auto writeA_f32 = [&](char* dstA, const float4* ar) {
    s8v p0, p1;
    p0[0] = (short)f2bf(ar[0].x); p0[1] = (short)f2bf(ar[0].y);
    p0[2] = (short)f2bf(ar[0].z); p0[3] = (short)f2bf(ar[0].w);
    p0[4] = (short)f2bf(ar[1].x); p0[5] = (short)f2bf(ar[1].y);
    p0[6] = (short)f2bf(ar[1].z); p0[7] = (short)f2bf(ar[1].w);
    p1[0] = (short)f2bf(ar[2].x); p1[1] = (short)f2bf(ar[2].y);
    p1[2] = (short)f2bf(ar[2].z); p1[3] = (short)f2bf(ar[2].w);
    p1[4] = (short)f2bf(ar[3].x); p1[5] = (short)f2bf(ar[3].y);
    p1[6] = (short)f2bf(ar[3].z); p1[7] = (short)f2bf(ar[3].w);
    *(s8v*)(dstA + (rAf * 8 + phys0) * 16) = p0;
    *(s8v*)(dstA + (rAf * 8 + (phys0 ^ 1)) * 16) = p1;
  };

  // --- prologue: stage tile 0 into buffer 0 ---
  stageB(smem + B_BASE, 0);
  if (A_FP32) {
    float4 ar[4];
    loadA_f32(0, ar);
    writeA_f32(smem, ar);
  } else {
    stageA_bf16(smem, 0);
  }
  __syncthreads();

  int cur = 0;
#pragma unroll 1
  for (int tt = 0; tt < NT; ++tt) {
    char* const Ac = smem + cur * A_BUF_SZ;
    char* const Bc = smem + B_BASE + cur * B_BUF_SZ;
    char* const An = smem + (cur ^ 1) * A_BUF_SZ;
    char* const Bn = smem + B_BASE + (cur ^ 1) * B_BUF_SZ;
    const bool more = (tt + 1 < NT);

    float4 ar[4];
    if (more) {                      // issue next-tile loads BEFORE compute
      stageB(Bn, (tt + 1) * 64);
      if (A_FP32) loadA_f32((tt + 1) * 64, ar);
      else stageA_bf16(An, (tt + 1) * 64);
    }

    // compute current tile: 2 x (8 ds_read_b128 + 16 MFMA)
#pragma unroll
    for (int ksub = 0; ksub < 2; ++ksub) {
      const int spx = (ksub * 4 + half) ^ (lane15 & 7);
      s8v af[4], bv[4];
#pragma unroll
      for (int ms = 0; ms < 4; ++ms)
        af[ms] = *(const s8v*)(Ac + (ms * 16 + lane15) * 128 + spx * 16);
#pragma unroll
      for (int ns = 0; ns < 4; ++ns)
        bv[ns] = *(const s8v*)(Bc + (w * 64 + ns * 16 + lane15) * 128 + spx * 16);
#pragma unroll
      for (int ms = 0; ms < 4; ++ms)
#pragma unroll
        for (int ns = 0; ns < 4; ++ns)
          acc[ms][ns] =
              __builtin_amdgcn_mfma_f32_16x16x32_bf16(af[ms], bv[ns], acc[ms][ns], 0, 0, 0);
    }

    if (more) {
      if (A_FP32) writeA_f32(An, ar);   // write-late (vmcnt waited here, after compute)
      __syncthreads();                  // drains vmcnt+lgkmcnt: next tile ready
    }
    cur ^= 1;
  }

  // --- epilogue ---
#pragma unroll
  for (int ms = 0; ms < 4; ++ms)
#pragma unroll
    for (int ns = 0; ns < 4; ++ns) {
      const int col = w * 64 + ns * 16 + lane15;
      f32x4 v = acc[ms][ns];
      if (BIAS_EN) {
#pragma unroll
        for (int r = 0; r < 4; ++r) v[r] += bias_l[ns];
      }
      if (RELU_EN) {
#pragma unroll
        for (int r = 0; r < 4; ++r) v[r] = fmaxf(v[r], 0.f);
      }
#pragma unroll
      for (int r = 0; r < 4; ++r) {
        const int row = bm + ms * 16 + half * 4 + r;
        if (row < M) Cp[(size_t)row * CSTRIDE + CBASE + col] = f2bf(v[r]);
      }
    }
}

// ------------------------------- gathers -----------------------------------
// one wave per node: mean of in-neighbor H2 rows (bf16, Acat cols 256..511)
__global__ __launch_bounds__(256) void gather_mean256_kernel(
    unsigned short* __restrict__ Acat, const int* __restrict__ rowptr,
    const unsigned short* __restrict__ eidx, int M) {
  const int node = blockIdx.x * 4 + (threadIdx.x >> 6);
  if (node >= M) return;
  const int lane = threadIdx.x & 63;
  const int c4 = lane * 4;
  const int beg = rowptr[node], end = rowptr[node + 1];
  float a0 = 0.f, a1 = 0.f, a2 = 0.f, a3 = 0.f;
  int j = beg;
  for (; j + 3 < end; j += 4) {
    const size_t s0 = eidx[j], s1 = eidx[j + 1], s2 = eidx[j + 2], s3 = eidx[j + 3];
    const ushort4 v0 = *(const ushort4*)(Acat + s0 * 512 + 256 + c4);
    const ushort4 v1 = *(const ushort4*)(Acat + s1 * 512 + 256 + c4);
    const ushort4 v2 = *(const ushort4*)(Acat + s2 * 512 + 256 + c4);
    const ushort4 v3 = *(const ushort4*)(Acat + s3 * 512 + 256 + c4);
    a0 += (bf2f(v0.x) + bf2f(v1.x)) + (bf2f(v2.x) + bf2f(v3.x));
    a1 += (bf2f(v0.y) + bf2f(v1.y)) + (bf2f(v2.y) + bf2f(v3.y));
    a2 += (bf2f(v0.z) + bf2f(v1.z)) + (bf2f(v2.z) + bf2f(v3.z));
    a3 += (bf2f(v0.w) + bf2f(v1.w)) + (bf2f(v2.w) + bf2f(v3.w));
  }
  for (; j < end; ++j) {
    const size_t s0 = eidx[j];
    const ushort4 v0 = *(const ushort4*)(Acat + s0 * 512 + 256 + c4);
    a0 += bf2f(v0.x); a1 += bf2f(v0.y); a2 += bf2f(v0.z); a3 += bf2f(v0.w);
  }
  const float inv = 1.0f / fmaxf((float)(end - beg), 1.0f);
  ushort4 o;
  o.x = f2bf(a0 * inv); o.y = f2bf(a1 * inv);
  o.z = f2bf(a2 * inv); o.w = f2bf(a3 * inv);
  *(ushort4*)(Acat + (size_t)node * 512 + c4) = o;
}

// one wave per node: v = mean(T[src]) + bl2 + R ; out = v / max(||v||,1e-12)
// T = Acat cols 256..383, R = Acat cols 384..511
__global__ __launch_bounds__(256) void gather_finalize_kernel(
    const unsigned short* __restrict__ Acat, const int* __restrict__ rowptr,
    const unsigned short* __restrict__ eidx, const float* __restrict__ bl2,
    float* __restrict__ out, int M) {
  const int node = blockIdx.x * 4 + (threadIdx.x >> 6);
  if (node >= M) return;
  const int lane = threadIdx.x & 63;
  const int c2 = lane * 2;
  const int beg = rowptr[node], end = rowptr[node + 1];
  float ax = 0.f, ay = 0.f;
  int j = beg;
  for (; j + 3 < end; j += 4) {
    const size_t s0 = eidx[j], s1 = eidx[j + 1], s2 = eidx[j + 2], s3 = eidx[j + 3];
    const ushort2 v0 = *(const ushort2*)(Acat + s0 * 512 + 256 + c2);
    const ushort2 v1 = *(const ushort2*)(Acat + s1 * 512 + 256 + c2);
    const ushort2 v2 = *(const ushort2*)(Acat + s2 * 512 + 256 + c2);
    const ushort2 v3 = *(const ushort2*)(Acat + s3 * 512 + 256 + c2);
    ax += (bf2f(v0.x) + bf2f(v1.x)) + (bf2f(v2.x) + bf2f(v3.x));
    ay += (bf2f(v0.y) + bf2f(v1.y)) + (bf2f(v2.y) + bf2f(v3.y));
  }
  for (; j < end; ++j) {
    const size_t s0 = eidx[j];
    const ushort2 v0 = *(const ushort2*)(Acat + s0 * 512 + 256 + c2);
    ax += bf2f(v0.x); ay += bf2f(v0.y);
  }
  const float inv = 1.0f / fmaxf((float)(end - beg), 1.0f);
  const ushort2 rr = *(const ushort2*)(Acat + (size_t)node * 512 + 384 + c2);
  const float2 b = *(const float2*)&bl2[c2];
  const float vx = fmaf(ax, inv, b.x) + bf2f(rr.x);
  const float vy = fmaf(ay, inv, b.y) + bf2f(rr.y);
  float ss = vx * vx + vy * vy;
#pragma unroll
  for (int off = 32; off > 0; off >>= 1) ss += __shfl_xor(ss, off);
  const float rn = 1.0f / fmaxf(sqrtf(ss), 1e-12f);
  *(float2*)&out[(size_t)node * 128 + c2] = make_float2(vx * rn, vy * rn);
}

// ---------------------------------------------------------------------------
extern "C" void kernel_launch(void* const* d_in, const int* in_sizes, int n_in,
                              void* d_out, int out_size, void* d_ws, size_t ws_size,
                              hipStream_t stream) {
  const float* x      = (const float*)d_in[0];
  const int*   ei     = (const int*)d_in[1];
  const float* W_pre  = (const float*)d_in[2];
  const float* b_pre  = (const float*)d_in[3];
  const float* W_pre2 = (const float*)d_in[4];
  const float* b_pre2 = (const float*)d_in[5];
  const float* Wl1    = (const float*)d_in[6];
  const float* bl1    = (const float*)d_in[7];
  const float* Wr1    = (const float*)d_in[8];
  const float* Wl2    = (const float*)d_in[9];
  const float* bl2    = (const float*)d_in[10];
  const float* Wr2    = (const float*)d_in[11];
  float* out = (float*)d_out;

  const int M = in_sizes[0] / 512;  // 50000
  const int E = in_sizes[1] / 2;    // 800000
  const int* src = ei;
  const int* dst = ei + E;

  // workspace: Acat bf16[M*512] | H3 bf16[M*256] | Wc[256*512] | Bc1[256*512]
  //   | Bc2[256*256] | bc f32[256] | rowptr[M+1] | cnt[M] | bsum | boff |
  //   eidx ushort[E]   (~80 MB)
  char* p = (char*)d_ws;
  unsigned short* Acat = (unsigned short*)p; p += (size_t)M * 512 * 2;
  unsigned short* H3   = (unsigned short*)p; p += (size_t)M * 256 * 2;
  unsigned short* Wc   = (unsigned short*)p; p += 256 * 512 * 2;
  unsigned short* Bc1  = (unsigned short*)p; p += 256 * 512 * 2;
  unsigned short* Bc2  = (unsigned short*)p; p += 256 * 256 * 2;
  float* bc   = (float*)p; p += 256 * 4;
  int* rowptr = (int*)p;   p += (size_t)(M + 1) * 4;
  int* cnt    = (int*)p;   p += (size_t)M * 4;
  int* bsum   = (int*)p;   p += 256 * 4;
  int* boff   = (int*)p;   p += 256 * 4;
  unsigned short* eidx = (unsigned short*)p;

  const int eblk = (E + 255) / 256;
  const int nb   = (M + 255) / 256;   // 196
  const int gx   = (M + 63) / 64;     // 782
  const int nblk = (M + 3) / 4;

  // CSR build
  zero_int_kernel<<<256, 256, 0, stream>>>(cnt, M);
  count_kernel<<<eblk, 256, 0, stream>>>(dst, cnt, E);
  scan_pass1<<<nb, 256, 0, stream>>>(cnt, bsum, M);
  scan_pass2<<<1, 256, 0, stream>>>(bsum, boff, rowptr, nb, M, E);
  scan_pass3<<<nb, 256, 0, stream>>>(cnt, boff, rowptr, M);
  fill_kernel<<<eblk, 256, 0, stream>>>(src, dst, rowptr, cnt, eidx, E);

  // fused weight prep
  prep_kernel<<<1025, 256, 0, stream>>>(W_pre, W_pre2, b_pre, b_pre2,
                                        Wl1, Wr1, Wl2, Wr2, Wc, bc, Bc1, Bc2);

  // H2 = x @ Wc.T + bc  -> Acat cols 256..511
  mfma_gemm<512, 512, 512, 256, true, false, true>
      <<<gx, 256, 0, stream>>>(x, Wc, bc, Acat, M);
  // mean1 -> Acat cols 0..255
  gather_mean256_kernel<<<nblk, 256, 0, stream>>>(Acat, rowptr, eidx, M);
  // H3 = relu(Acat @ Bc1.T + bl1)
  mfma_gemm<512, 512, 256, 0, true, true, false>
      <<<gx, 256, 0, stream>>>(Acat, Bc1, bl1, H3, M);
  // TR = H3 @ Bc2.T -> Acat cols 256..511 (H2 dead)
  mfma_gemm<256, 256, 512, 256, false, false, false>
      <<<gx, 256, 0, stream>>>(H3, Bc2, nullptr, Acat, M);
  // out = l2norm(mean(T) + bl2 + R)
  gather_finalize_kernel<<<nblk, 256, 0, stream>>>(Acat, rowptr, eidx, bl2, out, M);
}